// Round 2
// baseline (1820.929 us; speedup 1.0000x reference)
//
#include <hip/hip_runtime.h>
#include <hip/hip_bf16.h>

#define NTOK 49
#define HEADS 6
#define DIM 192
#define DH 32

typedef short s8v __attribute__((ext_vector_type(8)));
typedef float f4v __attribute__((ext_vector_type(4)));

#define MFMA16(a, b, c) __builtin_amdgcn_mfma_f32_16x16x32_bf16((a), (b), (c), 0, 0, 0)

__device__ inline short f2bf(float f) {
    __hip_bfloat16 h = __float2bfloat16(f);
    return __builtin_bit_cast(short, h);
}

// load 8 consecutive fp32, convert to bf16x8 fragment (16B-aligned source)
__device__ inline s8v ld_bf8(const float* __restrict__ p) {
    float4 f0 = *(const float4*)p;
    float4 f1 = *(const float4*)(p + 4);
    s8v r;
    r[0] = f2bf(f0.x); r[1] = f2bf(f0.y); r[2] = f2bf(f0.z); r[3] = f2bf(f0.w);
    r[4] = f2bf(f1.x); r[5] = f2bf(f1.y); r[6] = f2bf(f1.z); r[7] = f2bf(f1.w);
    return r;
}

__global__ __launch_bounds__(512) void winattn_kernel(
    const float* __restrict__ x,
    const float* __restrict__ qkv_w,
    const float* __restrict__ qkv_b,
    const float* __restrict__ proj_w,
    const float* __restrict__ proj_b,
    const float* __restrict__ bias_table,
    const int* __restrict__ rel_idx,
    float* __restrict__ out)
{
    // LDS staging (bf16). Strides padded: every fragment read 16B-aligned,
    // lane->bank aliasing <=2-way (free per m136).
    __shared__ __align__(16) short xs[64 * 200];  // x tile, rows 49..63 zeroed
    __shared__ __align__(16) short qs[64 * 40];   // q (pre-scaled); reused as O_h
    __shared__ __align__(16) short ks[64 * 40];   // k
    __shared__ __align__(16) short vs[32 * 72];   // v^T: [d][token]
    __shared__ __align__(16) short ps[64 * 72];   // softmax P (A-operand layout)

    const int tid  = threadIdx.x;
    const int w    = tid >> 6;       // wave 0..7
    const int lane = tid & 63;
    const int quad = lane >> 4;
    const int l16  = lane & 15;
    const int b    = blockIdx.x;

    const int mt   = w & 3;          // M-tile (token rows 16*mt..16*mt+15)
    const int half = w >> 2;         // 0/1 split of N work

    // ---- phase 0: stage x window (49x192 fp32) -> bf16 LDS; zero pad rows
    {
        const float4* src = (const float4*)(x + (size_t)b * NTOK * DIM);
        for (int idx = tid; idx < 2352; idx += 512) {      // 49 rows * 48 chunks
            int n = idx / 48, c = idx % 48;
            float4 f = src[idx];
            short* dst = &xs[n * 200 + c * 4];
            dst[0] = f2bf(f.x); dst[1] = f2bf(f.y);
            dst[2] = f2bf(f.z); dst[3] = f2bf(f.w);
        }
        int* xz = (int*)xs;
        for (int i = tid; i < 1500; i += 512) xz[4900 + i] = 0;  // rows 49..63
    }
    __syncthreads();

    f4v acc_p[6];
    for (int i = 0; i < 6; i++) acc_p[i] = (f4v){0.f, 0.f, 0.f, 0.f};

    for (int h = 0; h < HEADS; ++h) {
        // ---- QKV GEMM: (64x192) @ 96 rows of qkv_w, per wave: M-tile mt, 3 N-tiles
        {
            f4v acc[3];
            for (int i = 0; i < 3; i++) acc[i] = (f4v){0.f, 0.f, 0.f, 0.f};
            int jbase[3];
            for (int i = 0; i < 3; i++) {
                int tn = half * 3 + i;                 // 0..5: q0 q1 k0 k1 v0 v1
                int t = tn >> 1, dpart = (tn & 1) * 16;
                jbase[i] = t * DIM + h * DH + dpart + l16;
            }
            for (int kb = 0; kb < 6; ++kb) {
                s8v a = *(const s8v*)&xs[(mt * 16 + l16) * 200 + kb * 32 + quad * 8];
                for (int i = 0; i < 3; i++) {
                    s8v bf = ld_bf8(qkv_w + jbase[i] * DIM + kb * 32 + quad * 8);
                    acc[i] = MFMA16(a, bf, acc[i]);
                }
            }
            for (int i = 0; i < 3; i++) {
                int tn = half * 3 + i;
                int t = tn >> 1, dpart = (tn & 1) * 16;
                float bias = qkv_b[jbase[i]];
                for (int r = 0; r < 4; r++) {
                    int row = mt * 16 + quad * 4 + r;
                    float v = acc[i][r] + bias;
                    if (t == 0)      qs[row * 40 + dpart + l16] = f2bf(v * 0.17677669529663689f);
                    else if (t == 1) ks[row * 40 + dpart + l16] = f2bf(v);
                    else             vs[(dpart + l16) * 72 + row] = f2bf(v);
                }
            }
        }
        __syncthreads();

        // ---- S = q @ k^T (+bias, mask) + softmax; waves 0..3, wave = M-tile
        if (w < 4) {
            f4v sacc[4];
            for (int i = 0; i < 4; i++) sacc[i] = (f4v){0.f, 0.f, 0.f, 0.f};
            s8v a = *(const s8v*)&qs[(w * 16 + l16) * 40 + quad * 8];
            for (int nt = 0; nt < 4; nt++) {
                s8v bf = *(const s8v*)&ks[(nt * 16 + l16) * 40 + quad * 8];
                sacc[nt] = MFMA16(a, bf, sacc[nt]);
            }
            for (int r = 0; r < 4; r++) {
                int row = w * 16 + quad * 4 + r;
                float sv[4];
                for (int nt = 0; nt < 4; nt++) {
                    int col = nt * 16 + l16;
                    float s = sacc[nt][r];
                    if (col < NTOK) {
                        if (row < NTOK) {
                            int ri = rel_idx[row * NTOK + col];
                            s += bias_table[ri * HEADS + h];
                        }
                    } else {
                        s = -30000.f;   // mask pad key tokens -> exp == 0
                    }
                    sv[nt] = s;
                }
                float m = fmaxf(fmaxf(sv[0], sv[1]), fmaxf(sv[2], sv[3]));
                for (int d = 1; d < 16; d <<= 1) m = fmaxf(m, __shfl_xor(m, d));
                float p[4], sum = 0.f;
                for (int nt = 0; nt < 4; nt++) {
                    p[nt] = exp2f((sv[nt] - m) * 1.4426950408889634f);
                    sum += p[nt];
                }
                for (int d = 1; d < 16; d <<= 1) sum += __shfl_xor(sum, d);
                float inv = 1.f / sum;
                for (int nt = 0; nt < 4; nt++)
                    ps[row * 72 + nt * 16 + l16] = f2bf(p[nt] * inv);
            }
        }
        __syncthreads();

        // ---- O_h = P @ V (K = 64 padded); per wave: M-tile mt, N-tile half
        {
            f4v oacc = (f4v){0.f, 0.f, 0.f, 0.f};
            for (int kb = 0; kb < 2; kb++) {
                s8v a  = *(const s8v*)&ps[(mt * 16 + l16) * 72 + kb * 32 + quad * 8];
                s8v bf = *(const s8v*)&vs[(half * 16 + l16) * 72 + kb * 32 + quad * 8];
                oacc = MFMA16(a, bf, oacc);
            }
            for (int r = 0; r < 4; r++) {
                int row = mt * 16 + quad * 4 + r;
                qs[row * 40 + half * 16 + l16] = f2bf(oacc[r]);  // q dead; barrier above
            }
        }
        __syncthreads();

        // ---- proj partial: acc_p += O_h @ proj_w[:, h*32:(h+1)*32]^T
        {
            s8v a = *(const s8v*)&qs[(mt * 16 + l16) * 40 + quad * 8];
            for (int i = 0; i < 6; i++) {
                int ncol = half * 96 + i * 16 + l16;
                s8v bf = ld_bf8(proj_w + ncol * DIM + h * DH + quad * 8);
                acc_p[i] = MFMA16(a, bf, acc_p[i]);
            }
        }
        __syncthreads();   // protect qs/ks/vs before next head's QKV writes
    }

    // ---- epilogue: + proj_b, store fp32
    for (int i = 0; i < 6; i++) {
        int ncol = half * 96 + i * 16 + l16;
        float bias = proj_b[ncol];
        for (int r = 0; r < 4; r++) {
            int row = mt * 16 + quad * 4 + r;
            if (row < NTOK)
                out[((size_t)b * NTOK + row) * DIM + ncol] = acc_p[i][r] + bias;
        }
    }
}

extern "C" void kernel_launch(void* const* d_in, const int* in_sizes, int n_in,
                              void* d_out, int out_size, void* d_ws, size_t ws_size,
                              hipStream_t stream) {
    const float* x          = (const float*)d_in[0];
    const float* qkv_w      = (const float*)d_in[1];
    const float* qkv_b      = (const float*)d_in[2];
    const float* proj_w     = (const float*)d_in[3];
    const float* proj_b     = (const float*)d_in[4];
    const float* bias_table = (const float*)d_in[5];
    const int*   rel_idx    = (const int*)d_in[6];
    float*       out        = (float*)d_out;

    const int B_ = in_sizes[0] / (NTOK * DIM);   // 4096
    winattn_kernel<<<dim3(B_), dim3(512), 0, stream>>>(
        x, qkv_w, qkv_b, proj_w, proj_b, bias_table, rel_idx, out);
}

// Round 3
// 952.366 us; speedup vs baseline: 1.9120x; 1.9120x over previous
//
#include <hip/hip_runtime.h>
#include <hip/hip_bf16.h>

#define NTOK 49
#define HEADS 6
#define DIM 192
#define DH 32

typedef short s8v __attribute__((ext_vector_type(8)));
typedef float f4v __attribute__((ext_vector_type(4)));

#define MFMA16(a, b, c) __builtin_amdgcn_mfma_f32_16x16x32_bf16((a), (b), (c), 0, 0, 0)

__device__ inline short f2bf(float f) {
    __hip_bfloat16 h = __float2bfloat16(f);
    return __builtin_bit_cast(short, h);
}

__device__ inline s8v ld_bf8(const float* __restrict__ p) {
    float4 f0 = *(const float4*)p;
    float4 f1 = *(const float4*)(p + 4);
    s8v r;
    r[0] = f2bf(f0.x); r[1] = f2bf(f0.y); r[2] = f2bf(f0.z); r[3] = f2bf(f0.w);
    r[4] = f2bf(f1.x); r[5] = f2bf(f1.y); r[6] = f2bf(f1.z); r[7] = f2bf(f1.w);
    return r;
}

// ============================ kernel 0: prep ================================
// qkv_w, proj_w -> bf16; biasM[h][r][c] = bias_table[rel_idx[r*49+c]*6+h] (fp32)
__global__ void prep_kernel(const float* __restrict__ qkv_w,
                            const float* __restrict__ proj_w,
                            const float* __restrict__ bias_table,
                            const int* __restrict__ rel_idx,
                            short* __restrict__ wq, short* __restrict__ wp,
                            float* __restrict__ biasM) {
    int tid = blockIdx.x * blockDim.x + threadIdx.x;
    int stride = gridDim.x * blockDim.x;
    for (int i = tid; i < 3 * DIM * DIM; i += stride) wq[i] = f2bf(qkv_w[i]);
    for (int i = tid; i < DIM * DIM; i += stride)     wp[i] = f2bf(proj_w[i]);
    for (int i = tid; i < HEADS * NTOK * NTOK; i += stride) {
        int h = i / (NTOK * NTOK), rc = i - h * (NTOK * NTOK);
        biasM[i] = bias_table[rel_idx[rc] * HEADS + h];
    }
}

// ============================ kernel 1: QKV =================================
// per window: q_ws[b][h][49][32] (scaled), k_ws same, v_ws = v^T [b][h][32][64]
__global__ __launch_bounds__(512) void qkv_kernel(
    const float* __restrict__ x, const short* __restrict__ wq,
    const float* __restrict__ qkv_b,
    short* __restrict__ q_ws, short* __restrict__ k_ws, short* __restrict__ v_ws)
{
    __shared__ __align__(16) short xs[64 * 200];
    __shared__ __align__(16) short vbuf[192 * 72];   // [h*32+d][token]

    const int tid = threadIdx.x, w = tid >> 6, lane = tid & 63;
    const int quad = lane >> 4, l16 = lane & 15, b = blockIdx.x;

    {   // stage x (fp32 -> bf16), zero pad rows
        const float4* src = (const float4*)(x + (size_t)b * NTOK * DIM);
        for (int idx = tid; idx < 2352; idx += 512) {
            int n = idx / 48, c = idx % 48;
            float4 f = src[idx];
            short* dst = &xs[n * 200 + c * 4];
            dst[0] = f2bf(f.x); dst[1] = f2bf(f.y);
            dst[2] = f2bf(f.z); dst[3] = f2bf(f.w);
        }
        int* xz = (int*)xs;
        for (int i = tid; i < 1500; i += 512) xz[4900 + i] = 0;
        // zero vbuf pad tokens 49..71 (rows never written by epilogue)
        for (int i = tid; i < 192 * 23; i += 512) {
            int row = i / 23, t = 49 + i % 23;
            vbuf[row * 72 + t] = 0;
        }
    }
    __syncthreads();

    for (int task = w; task < 144; task += 8) {       // 4 mt x 36 nt
        int mt = task & 3, nt = task >> 2;
        f4v acc = (f4v){0.f, 0.f, 0.f, 0.f};
        const short* wrow = wq + (nt * 16 + l16) * DIM;
        for (int kb = 0; kb < 6; ++kb) {
            s8v a  = *(const s8v*)&xs[(mt * 16 + l16) * 200 + kb * 32 + quad * 8];
            s8v bw = *(const s8v*)(wrow + kb * 32 + quad * 8);
            acc = MFMA16(a, bw, acc);
        }
        int t = nt / 12, hh = (nt % 12) >> 1, dh16 = (nt & 1) * 16;
        int j0 = nt * 16 + l16;
        float bias = qkv_b[j0];
        float scale = (t == 0) ? 0.17677669529663689f : 1.0f;
        for (int r = 0; r < 4; ++r) {
            int row = mt * 16 + quad * 4 + r;
            if (row < NTOK) {
                short val = f2bf((acc[r] + bias) * scale);
                size_t base = ((size_t)(b * HEADS + hh) * NTOK + row) * DH + dh16 + l16;
                if (t == 0)      q_ws[base] = val;
                else if (t == 1) k_ws[base] = val;
                else             vbuf[(hh * DH + dh16 + l16) * 72 + row] = val;
            }
        }
    }
    __syncthreads();

    {   // cooperative v^T store: 192 rows x 64 tokens, 16B chunks
        short* dstbase = v_ws + (size_t)b * 192 * 64;
        for (int c = tid; c < 1536; c += 512) {
            int row = c >> 3, tk = (c & 7) * 8;
            *(int4*)(dstbase + row * 64 + tk) = *(const int4*)&vbuf[row * 72 + tk];
        }
    }
}

// ============================ kernel 2: attention ===========================
// block = window, wave = head; one barrier (before O overwrites q region)
__global__ __launch_bounds__(384) void attn_kernel(
    const short* __restrict__ k_ws, const short* __restrict__ v_ws,
    const float* __restrict__ biasM, short* qo_ws /* q in, O out (aliased) */)
{
    __shared__ __align__(16) short ps[6 * 64 * 72];

    const int tid = threadIdx.x, w = tid >> 6, lane = tid & 63;
    const int quad = lane >> 4, l16 = lane & 15, b = blockIdx.x;
    const int h = w;
    short* psw = ps + w * 4608;

    const short* qb = qo_ws + (size_t)(b * HEADS + h) * NTOK * DH;
    const short* kb = k_ws  + (size_t)(b * HEADS + h) * NTOK * DH;
    const short* vb = v_ws  + (size_t)(b * HEADS + h) * DH * 64;

    s8v aq[4], bk[4];
    for (int i = 0; i < 4; ++i)
        aq[i] = *(const s8v*)(qb + (i * 16 + l16) * DH + quad * 8);
    for (int i = 0; i < 4; ++i)
        bk[i] = *(const s8v*)(kb + (i * 16 + l16) * DH + quad * 8);

    f4v sacc[4][4];
    for (int mt = 0; mt < 4; ++mt)
        for (int nt = 0; nt < 4; ++nt)
            sacc[mt][nt] = MFMA16(aq[mt], bk[nt], ((f4v){0.f, 0.f, 0.f, 0.f}));

    const float* bmh = biasM + h * (NTOK * NTOK);
    for (int mt = 0; mt < 4; ++mt)
        for (int r = 0; r < 4; ++r) {
            int row = mt * 16 + quad * 4 + r;
            float sv[4];
            for (int nt = 0; nt < 4; ++nt) {
                int col = nt * 16 + l16;
                float s = sacc[mt][nt][r];
                if (col < NTOK) {
                    if (row < NTOK) s += bmh[row * NTOK + col];
                } else s = -30000.f;
                sv[nt] = s;
            }
            float m = fmaxf(fmaxf(sv[0], sv[1]), fmaxf(sv[2], sv[3]));
            for (int d = 1; d < 16; d <<= 1) m = fmaxf(m, __shfl_xor(m, d));
            float p[4], sum = 0.f;
            for (int nt = 0; nt < 4; ++nt) {
                p[nt] = exp2f((sv[nt] - m) * 1.4426950408889634f);
                sum += p[nt];
            }
            for (int d = 1; d < 16; d <<= 1) sum += __shfl_xor(sum, d);
            float inv = 1.f / sum;
            for (int nt = 0; nt < 4; ++nt)
                psw[row * 72 + nt * 16 + l16] = f2bf(p[nt] * inv);
        }

    f4v oacc[4][2];
    for (int mt = 0; mt < 4; ++mt)
        for (int nv = 0; nv < 2; ++nv) oacc[mt][nv] = (f4v){0.f, 0.f, 0.f, 0.f};
    for (int ks = 0; ks < 2; ++ks) {
        s8v bv[2];
        for (int nv = 0; nv < 2; ++nv)
            bv[nv] = *(const s8v*)(vb + (nv * 16 + l16) * 64 + ks * 32 + quad * 8);
        for (int mt = 0; mt < 4; ++mt) {
            s8v ap = *(const s8v*)&psw[(mt * 16 + l16) * 72 + ks * 32 + quad * 8];
            for (int nv = 0; nv < 2; ++nv)
                oacc[mt][nv] = MFMA16(ap, bv[nv], oacc[mt][nv]);
        }
    }

    __syncthreads();   // all q/k/v global reads done before O overwrites q region

    for (int mt = 0; mt < 4; ++mt)
        for (int nv = 0; nv < 2; ++nv)
            for (int r = 0; r < 4; ++r) {
                int row = mt * 16 + quad * 4 + r;
                if (row < NTOK)
                    qo_ws[((size_t)(b * NTOK + row) * HEADS + h) * DH + nv * 16 + l16] =
                        f2bf(oacc[mt][nv][r]);
            }
}

// ============================ kernel 3: proj ================================
__global__ __launch_bounds__(512) void proj_kernel(
    const short* __restrict__ o_ws, const short* __restrict__ wp,
    const float* __restrict__ proj_b, float* __restrict__ out)
{
    __shared__ __align__(16) short os[64 * 200];
    const int tid = threadIdx.x, w = tid >> 6, lane = tid & 63;
    const int quad = lane >> 4, l16 = lane & 15, b = blockIdx.x;

    {
        const short* src = o_ws + (size_t)b * NTOK * DIM;
        for (int c = tid; c < 1176; c += 512) {
            int n = c / 24, cc = (c % 24) * 8;
            *(int4*)&os[n * 200 + cc] = *(const int4*)(src + n * DIM + cc);
        }
        int* oz = (int*)os;
        for (int i = tid; i < 1500; i += 512) oz[4900 + i] = 0;
    }
    __syncthreads();

    for (int task = w; task < 48; task += 8) {       // 4 mt x 12 nt
        int mt = task & 3, nt = task >> 2;
        f4v acc = (f4v){0.f, 0.f, 0.f, 0.f};
        const short* wrow = wp + (nt * 16 + l16) * DIM;
        for (int kb = 0; kb < 6; ++kb) {
            s8v a  = *(const s8v*)&os[(mt * 16 + l16) * 200 + kb * 32 + quad * 8];
            s8v bw = *(const s8v*)(wrow + kb * 32 + quad * 8);
            acc = MFMA16(a, bw, acc);
        }
        int j0 = nt * 16 + l16;
        float bias = proj_b[j0];
        for (int r = 0; r < 4; ++r) {
            int row = mt * 16 + quad * 4 + r;
            if (row < NTOK)
                out[((size_t)b * NTOK + row) * DIM + j0] = acc[r] + bias;
        }
    }
}

// ===================== fallback: round-2 fused kernel =======================
__global__ __launch_bounds__(512) void winattn_fused(
    const float* __restrict__ x, const float* __restrict__ qkv_w,
    const float* __restrict__ qkv_b, const float* __restrict__ proj_w,
    const float* __restrict__ proj_b, const float* __restrict__ bias_table,
    const int* __restrict__ rel_idx, float* __restrict__ out)
{
    __shared__ __align__(16) short xs[64 * 200];
    __shared__ __align__(16) short qs[64 * 40];
    __shared__ __align__(16) short ks[64 * 40];
    __shared__ __align__(16) short vs[32 * 72];
    __shared__ __align__(16) short pp[64 * 72];

    const int tid = threadIdx.x, w = tid >> 6, lane = tid & 63;
    const int quad = lane >> 4, l16 = lane & 15, b = blockIdx.x;
    const int mt = w & 3, half = w >> 2;

    {
        const float4* src = (const float4*)(x + (size_t)b * NTOK * DIM);
        for (int idx = tid; idx < 2352; idx += 512) {
            int n = idx / 48, c = idx % 48;
            float4 f = src[idx];
            short* dst = &xs[n * 200 + c * 4];
            dst[0] = f2bf(f.x); dst[1] = f2bf(f.y);
            dst[2] = f2bf(f.z); dst[3] = f2bf(f.w);
        }
        int* xz = (int*)xs;
        for (int i = tid; i < 1500; i += 512) xz[4900 + i] = 0;
    }
    __syncthreads();

    f4v acc_p[6];
    for (int i = 0; i < 6; i++) acc_p[i] = (f4v){0.f, 0.f, 0.f, 0.f};

    for (int h = 0; h < HEADS; ++h) {
        {
            f4v acc[3];
            for (int i = 0; i < 3; i++) acc[i] = (f4v){0.f, 0.f, 0.f, 0.f};
            int jbase[3];
            for (int i = 0; i < 3; i++) {
                int tn = half * 3 + i;
                int t = tn >> 1, dpart = (tn & 1) * 16;
                jbase[i] = t * DIM + h * DH + dpart + l16;
            }
            for (int kb2 = 0; kb2 < 6; ++kb2) {
                s8v a = *(const s8v*)&xs[(mt * 16 + l16) * 200 + kb2 * 32 + quad * 8];
                for (int i = 0; i < 3; i++) {
                    s8v bf = ld_bf8(qkv_w + jbase[i] * DIM + kb2 * 32 + quad * 8);
                    acc[i] = MFMA16(a, bf, acc[i]);
                }
            }
            for (int i = 0; i < 3; i++) {
                int tn = half * 3 + i;
                int t = tn >> 1, dpart = (tn & 1) * 16;
                float bias = qkv_b[jbase[i]];
                for (int r = 0; r < 4; r++) {
                    int row = mt * 16 + quad * 4 + r;
                    float v = acc[i][r] + bias;
                    if (t == 0)      qs[row * 40 + dpart + l16] = f2bf(v * 0.17677669529663689f);
                    else if (t == 1) ks[row * 40 + dpart + l16] = f2bf(v);
                    else             vs[(dpart + l16) * 72 + row] = f2bf(v);
                }
            }
        }
        __syncthreads();
        if (w < 4) {
            f4v sacc[4];
            for (int i = 0; i < 4; i++) sacc[i] = (f4v){0.f, 0.f, 0.f, 0.f};
            s8v a = *(const s8v*)&qs[(w * 16 + l16) * 40 + quad * 8];
            for (int nt = 0; nt < 4; nt++) {
                s8v bf = *(const s8v*)&ks[(nt * 16 + l16) * 40 + quad * 8];
                sacc[nt] = MFMA16(a, bf, sacc[nt]);
            }
            for (int r = 0; r < 4; r++) {
                int row = w * 16 + quad * 4 + r;
                float sv[4];
                for (int nt = 0; nt < 4; nt++) {
                    int col = nt * 16 + l16;
                    float s = sacc[nt][r];
                    if (col < NTOK) {
                        if (row < NTOK)
                            s += bias_table[rel_idx[row * NTOK + col] * HEADS + h];
                    } else s = -30000.f;
                    sv[nt] = s;
                }
                float m = fmaxf(fmaxf(sv[0], sv[1]), fmaxf(sv[2], sv[3]));
                for (int d = 1; d < 16; d <<= 1) m = fmaxf(m, __shfl_xor(m, d));
                float p[4], sum = 0.f;
                for (int nt = 0; nt < 4; nt++) {
                    p[nt] = exp2f((sv[nt] - m) * 1.4426950408889634f);
                    sum += p[nt];
                }
                for (int d = 1; d < 16; d <<= 1) sum += __shfl_xor(sum, d);
                float inv = 1.f / sum;
                for (int nt = 0; nt < 4; nt++)
                    pp[row * 72 + nt * 16 + l16] = f2bf(p[nt] * inv);
            }
        }
        __syncthreads();
        {
            f4v oacc = (f4v){0.f, 0.f, 0.f, 0.f};
            for (int kb2 = 0; kb2 < 2; kb2++) {
                s8v a  = *(const s8v*)&pp[(mt * 16 + l16) * 72 + kb2 * 32 + quad * 8];
                s8v bf = *(const s8v*)&vs[(half * 16 + l16) * 72 + kb2 * 32 + quad * 8];
                oacc = MFMA16(a, bf, oacc);
            }
            for (int r = 0; r < 4; r++) {
                int row = mt * 16 + quad * 4 + r;
                qs[row * 40 + half * 16 + l16] = f2bf(oacc[r]);
            }
        }
        __syncthreads();
        {
            s8v a = *(const s8v*)&qs[(mt * 16 + l16) * 40 + quad * 8];
            for (int i = 0; i < 6; i++) {
                int ncol = half * 96 + i * 16 + l16;
                s8v bf = ld_bf8(proj_w + ncol * DIM + h * DH + quad * 8);
                acc_p[i] = MFMA16(a, bf, acc_p[i]);
            }
        }
        __syncthreads();
    }
    for (int i = 0; i < 6; i++) {
        int ncol = half * 96 + i * 16 + l16;
        float bias = proj_b[ncol];
        for (int r = 0; r < 4; r++) {
            int row = mt * 16 + quad * 4 + r;
            if (row < NTOK)
                out[((size_t)b * NTOK + row) * DIM + ncol] = acc_p[i][r] + bias;
        }
    }
}

// ============================================================================
extern "C" void kernel_launch(void* const* d_in, const int* in_sizes, int n_in,
                              void* d_out, int out_size, void* d_ws, size_t ws_size,
                              hipStream_t stream) {
    const float* x          = (const float*)d_in[0];
    const float* qkv_w      = (const float*)d_in[1];
    const float* qkv_b      = (const float*)d_in[2];
    const float* proj_w     = (const float*)d_in[3];
    const float* proj_b     = (const float*)d_in[4];
    const float* bias_table = (const float*)d_in[5];
    const int*   rel_idx    = (const int*)d_in[6];
    float*       out        = (float*)d_out;

    const int B_ = in_sizes[0] / (NTOK * DIM);   // 4096

    // workspace layout (bytes)
    const size_t sz_q  = (size_t)B_ * HEADS * NTOK * DH * 2;   // q / O aliased
    const size_t sz_k  = sz_q;
    const size_t sz_v  = (size_t)B_ * HEADS * DH * 64 * 2;     // v^T padded to 64
    const size_t sz_wq = (size_t)3 * DIM * DIM * 2;
    const size_t sz_wp = (size_t)DIM * DIM * 2;
    const size_t sz_bm = (size_t)HEADS * NTOK * NTOK * 4;
    const size_t need  = sz_q + sz_k + sz_v + sz_wq + sz_wp + sz_bm;

    if (ws_size >= need) {
        char* p = (char*)d_ws;
        short* q_ws  = (short*)p;                 p += sz_q;
        short* k_ws  = (short*)p;                 p += sz_k;
        short* v_ws  = (short*)p;                 p += sz_v;
        short* wq    = (short*)p;                 p += sz_wq;
        short* wp    = (short*)p;                 p += sz_wp;
        float* biasM = (float*)p;

        prep_kernel<<<dim3(128), dim3(256), 0, stream>>>(
            qkv_w, proj_w, bias_table, rel_idx, wq, wp, biasM);
        qkv_kernel<<<dim3(B_), dim3(512), 0, stream>>>(
            x, wq, qkv_b, q_ws, k_ws, v_ws);
        attn_kernel<<<dim3(B_), dim3(384), 0, stream>>>(
            k_ws, v_ws, biasM, q_ws);
        proj_kernel<<<dim3(B_), dim3(512), 0, stream>>>(
            q_ws, wp, proj_b, out);
    } else {
        winattn_fused<<<dim3(B_), dim3(512), 0, stream>>>(
            x, qkv_w, qkv_b, proj_w, proj_b, bias_table, rel_idx, out);
    }
}